// Round 1
// baseline (618.251 us; speedup 1.0000x reference)
//
#include <hip/hip_runtime.h>

// ---------------------------------------------------------------------------
// Att2in2Core: B=256, S=49, H=2048, V_SZ=10000
// d_in order (setup_inputs dict order):
//  0 V(B,S,H) 1 v_g 2 state(2,1,B,H) 3 captions(B,16) 4 time
//  5 fc_W 6 fc_b 7 att_W 8 att_b 9 emb 10 ctx_W 11 ctx_b 12 a2c_W 13 a2c_b
// 14 i2h_W 15 i2h_b 16 h2h_W 17 h2h_b 18 h2att_W 19 h2att_b 20 alpha_W 21 alpha_b
// fc_* / v_g are dead code in the reference; alpha_b is softmax-invariant.
// ---------------------------------------------------------------------------

typedef __bf16 bf16x8 __attribute__((ext_vector_type(8)));
typedef float  f32x4  __attribute__((ext_vector_type(4)));

static constexpr int Bn = 256;
static constexpr int Sn = 49;
static constexpr int Hn = 2048;
static constexpr int Mrows = Bn * Sn;      // 12544
static constexpr int LDP = 72;             // padded LDS row stride (bf16 elems)

__device__ __forceinline__ unsigned short f2bf(float f) {
    unsigned u = __builtin_bit_cast(unsigned, f);
    u += 0x7FFFu + ((u >> 16) & 1u);       // round-to-nearest-even
    return (unsigned short)(u >> 16);
}
__device__ __forceinline__ float bf2f(unsigned short h) {
    return __builtin_bit_cast(float, ((unsigned)h) << 16);
}

// -------------------- f32 -> bf16 bulk convert (8 elems/thread) ------------
__global__ void k_convert(const float* __restrict__ src,
                          unsigned short* __restrict__ dst, int n8) {
    int i = blockIdx.x * blockDim.x + threadIdx.x;
    if (i >= n8) return;
    const float4* p = (const float4*)src + (size_t)i * 2;
    float4 a = p[0], b = p[1];
    union { unsigned short us[8]; int4 v; } o;
    o.us[0] = f2bf(a.x); o.us[1] = f2bf(a.y); o.us[2] = f2bf(a.z); o.us[3] = f2bf(a.w);
    o.us[4] = f2bf(b.x); o.us[5] = f2bf(b.y); o.us[6] = f2bf(b.z); o.us[7] = f2bf(b.w);
    ((int4*)dst)[i] = o.v;
}

// -------------------- gather xt = relu(emb[captions[:,t]]), h_prev ----------
__global__ void k_gather(const float* __restrict__ emb,
                         const float* __restrict__ state,
                         const int* __restrict__ captions,
                         const int* __restrict__ timep,
                         unsigned short* __restrict__ xt_b,
                         unsigned short* __restrict__ h_b) {
    int b = blockIdx.x;
    int tm = timep[0];
    int it = captions[b * 16 + tm];
    const float* erow = emb + (size_t)it * Hn;
    for (int h = threadIdx.x; h < Hn; h += blockDim.x) {
        float x = erow[h];
        xt_b[(size_t)b * Hn + h] = f2bf(x > 0.f ? x : 0.f);
        float hv = (tm == 0) ? 0.f : state[(size_t)b * Hn + h];  // state[0,0,b,:]
        h_b[(size_t)b * Hn + h] = f2bf(hv);
    }
}

// -------------------- templated MFMA GEMM: C = A @ B^T (+ DUAL pair) --------
// A: bf16 (M,K) row-major. B: (N,K) row-major, bf16 or f32 (converted in staging).
// EPI 0: out_bf16 = relu(acc + bias[n])
// EPI 1: out_f32  = acc + bias[n] (+ bias2[n] if DUAL)
// EPI 3: scores[m] += sum_n tanh(acc + bias[n] + atth[m/49][n]) * alphaW[n]
template<int EPI, bool BF32, bool DUAL>
__global__ __launch_bounds__(256)
void k_gemm(const unsigned short* __restrict__ A, const void* __restrict__ B,
            const unsigned short* __restrict__ A2, const void* __restrict__ B2,
            const float* __restrict__ bias, const float* __restrict__ bias2,
            void* __restrict__ out,
            const float* __restrict__ atth, const float* __restrict__ alphaW,
            int M, int N, int K) {
    __shared__ __align__(16) unsigned short As[128 * LDP];
    __shared__ __align__(16) unsigned short Bs[128 * LDP];

    const int tid = threadIdx.x;
    const int m0 = blockIdx.y * 128;
    const int n0 = blockIdx.x * 128;
    const int lane = tid & 63;
    const int wave = tid >> 6;
    const int wm = (wave >> 1) * 64;   // wave row offset in tile
    const int wn = (wave & 1) * 64;    // wave col offset in tile

    f32x4 acc[4][4];
#pragma unroll
    for (int i = 0; i < 4; ++i)
#pragma unroll
        for (int j = 0; j < 4; ++j)
#pragma unroll
            for (int r = 0; r < 4; ++r) acc[i][j][r] = 0.f;

    const int npass = DUAL ? 2 : 1;
    for (int pass = 0; pass < npass; ++pass) {
        const unsigned short* Ap = pass ? A2 : A;
        const void* Bp = pass ? B2 : B;
        for (int kt = 0; kt < K; kt += 64) {
            __syncthreads();
            {   // stage A (bf16): 128 rows x 64 cols
                const int r = tid >> 3, c = (tid & 7) << 3;
                const unsigned short* src = Ap + (size_t)(m0 + r) * K + kt + c;
#pragma unroll
                for (int i = 0; i < 4; ++i) {
                    int4 v = *(const int4*)(src + (size_t)i * 32 * K);
                    *(int4*)&As[(r + i * 32) * LDP + c] = v;
                }
            }
            if (BF32) {  // stage B from f32, converting
                const int r = tid >> 4, c = (tid & 15) << 2;
                const float* src = (const float*)Bp + (size_t)(n0 + r) * K + kt + c;
#pragma unroll
                for (int i = 0; i < 8; ++i) {
                    float4 v = *(const float4*)(src + (size_t)i * 16 * K);
                    union { unsigned short us[4]; uint2 u2; } t;
                    t.us[0] = f2bf(v.x); t.us[1] = f2bf(v.y);
                    t.us[2] = f2bf(v.z); t.us[3] = f2bf(v.w);
                    *(uint2*)&Bs[(r + i * 16) * LDP + c] = t.u2;
                }
            } else {     // stage B (bf16)
                const int r = tid >> 3, c = (tid & 7) << 3;
                const unsigned short* src = (const unsigned short*)Bp + (size_t)(n0 + r) * K + kt + c;
#pragma unroll
                for (int i = 0; i < 4; ++i) {
                    int4 v = *(const int4*)(src + (size_t)i * 32 * K);
                    *(int4*)&Bs[(r + i * 32) * LDP + c] = v;
                }
            }
            __syncthreads();
            // compute: 2 k-substeps of 32, 16 MFMA each
#pragma unroll
            for (int ks = 0; ks < 64; ks += 32) {
                const int col = ks + ((lane >> 4) << 3);
                const int ra = wm + (lane & 15);
                const int rb = wn + (lane & 15);
                bf16x8 af[4], bfr[4];
#pragma unroll
                for (int i = 0; i < 4; ++i)
                    af[i] = *(const bf16x8*)&As[(ra + i * 16) * LDP + col];
#pragma unroll
                for (int j = 0; j < 4; ++j)
                    bfr[j] = *(const bf16x8*)&Bs[(rb + j * 16) * LDP + col];
#pragma unroll
                for (int i = 0; i < 4; ++i)
#pragma unroll
                    for (int j = 0; j < 4; ++j)
                        acc[i][j] = __builtin_amdgcn_mfma_f32_16x16x32_bf16(
                            af[i], bfr[j], acc[i][j], 0, 0, 0);
            }
        }
    }

    // epilogue — D layout (verified): col = lane&15, row = (lane>>4)*4 + r
#pragma unroll
    for (int i = 0; i < 4; ++i) {
#pragma unroll
        for (int r = 0; r < 4; ++r) {
            const int gm = m0 + wm + i * 16 + ((lane >> 4) << 2) + r;
            if constexpr (EPI == 3) {
                float partial = 0.f;
                const int b = gm / Sn;
#pragma unroll
                for (int j = 0; j < 4; ++j) {
                    const int gn = n0 + wn + j * 16 + (lane & 15);
                    float v = acc[i][j][r] + bias[gn] + atth[(size_t)b * N + gn];
                    partial += tanhf(v) * alphaW[gn];
                }
#pragma unroll
                for (int off = 1; off < 16; off <<= 1)
                    partial += __shfl_xor(partial, off);
                if ((lane & 15) == 0) atomicAdd(&((float*)out)[gm], partial);
            } else {
#pragma unroll
                for (int j = 0; j < 4; ++j) {
                    const int gn = n0 + wn + j * 16 + (lane & 15);
                    float v = acc[i][j][r] + bias[gn];
                    if (DUAL) v += bias2[gn];
                    if constexpr (EPI == 0) {
                        ((unsigned short*)out)[(size_t)gm * N + gn] = f2bf(v > 0.f ? v : 0.f);
                    } else {
                        ((float*)out)[(size_t)gm * N + gn] = v;
                    }
                }
            }
        }
    }
}

// -------------------- softmax over S=49 per batch row -----------------------
__global__ void k_softmax(const float* __restrict__ scores, float* __restrict__ weight) {
    int b = blockIdx.x;
    int s = threadIdx.x;  // 64 threads = 1 wave
    float v = (s < Sn) ? scores[b * Sn + s] : -1e30f;
    float m = v;
#pragma unroll
    for (int off = 1; off < 64; off <<= 1) m = fmaxf(m, __shfl_xor(m, off));
    float e = (s < Sn) ? __expf(v - m) : 0.f;
    float sum = e;
#pragma unroll
    for (int off = 1; off < 64; off <<= 1) sum += __shfl_xor(sum, off);
    if (s < Sn) weight[b * Sn + s] = e / sum;
}

// -------------------- att_res[b,h] = sum_s w[b,s] * att_feats[b,s,h] --------
__global__ void k_attres(const float* __restrict__ weight,
                         const unsigned short* __restrict__ attf,
                         unsigned short* __restrict__ attres) {
    int b = blockIdx.y;
    int h = blockIdx.x * blockDim.x + threadIdx.x;
    const unsigned short* p = attf + (size_t)b * Sn * Hn + h;
    float acc = 0.f;
#pragma unroll 7
    for (int s = 0; s < Sn; ++s)
        acc += weight[b * Sn + s] * bf2f(p[(size_t)s * Hn]);
    attres[(size_t)b * Hn + h] = f2bf(acc);
}

// -------------------- LSTM tail ---------------------------------------------
__global__ void k_final(const float* __restrict__ sums, const float* __restrict__ a2c,
                        const float* __restrict__ state, const int* __restrict__ timep,
                        float* __restrict__ out) {
    int idx = blockIdx.x * blockDim.x + threadIdx.x;  // over B*H
    int b = idx >> 11, h = idx & (Hn - 1);
    const float* srow = sums + (size_t)b * 5 * Hn;
    float ig = 1.f / (1.f + __expf(-srow[h]));
    float fg = 1.f / (1.f + __expf(-srow[Hn + h]));
    float og = 1.f / (1.f + __expf(-srow[2 * Hn + h]));
    float t1 = srow[3 * Hn + h] + a2c[(size_t)b * 2 * Hn + h];
    float t2 = srow[4 * Hn + h] + a2c[(size_t)b * 2 * Hn + Hn + h];
    float intr = fmaxf(t1, t2);
    float cprev = (timep[0] == 0) ? 0.f : state[(size_t)Bn * Hn + idx];  // state[1,0,b,:]
    float c = fg * cprev + ig * intr;
    float hh = og * tanhf(c);
    const int BH = Bn * Hn;
    out[idx] = hh;            // output (B,1,H)
    out[BH + idx] = hh;       // next_h (1,B,H)
    out[2 * BH + idx] = c;    // next_c (1,B,H)
}

// ---------------------------------------------------------------------------
extern "C" void kernel_launch(void* const* d_in, const int* in_sizes, int n_in,
                              void* d_out, int out_size, void* d_ws, size_t ws_size,
                              hipStream_t stream) {
    const float* V        = (const float*)d_in[0];
    const float* state    = (const float*)d_in[2];
    const int*   captions = (const int*)d_in[3];
    const int*   timep    = (const int*)d_in[4];
    const float* att_W    = (const float*)d_in[7];
    const float* att_b    = (const float*)d_in[8];
    const float* emb      = (const float*)d_in[9];
    const float* ctx_W    = (const float*)d_in[10];
    const float* ctx_b    = (const float*)d_in[11];
    const float* a2c_W    = (const float*)d_in[12];
    const float* a2c_b    = (const float*)d_in[13];
    const float* i2h_W    = (const float*)d_in[14];
    const float* i2h_b    = (const float*)d_in[15];
    const float* h2h_W    = (const float*)d_in[16];
    const float* h2h_b    = (const float*)d_in[17];
    const float* h2att_W  = (const float*)d_in[18];
    const float* h2att_b  = (const float*)d_in[19];
    const float* alpha_W  = (const float*)d_in[20];

    // workspace layout (bf16 elems first, then f32)
    unsigned short* Vb      = (unsigned short*)d_ws;        // 25,690,112
    unsigned short* attWb   = Vb + (size_t)Mrows * Hn;      //  4,194,304
    unsigned short* ctxWb   = attWb + (size_t)Hn * Hn;      //  4,194,304
    unsigned short* attfb   = ctxWb + (size_t)Hn * Hn;      // 25,690,112
    unsigned short* xtb     = attfb + (size_t)Mrows * Hn;   //    524,288
    unsigned short* hb      = xtb + Bn * Hn;                //    524,288
    unsigned short* attresb = hb + Bn * Hn;                 //    524,288
    float* atth    = (float*)(attresb + Bn * Hn);           //    524,288 f32
    float* scores  = atth + Bn * Hn;                        //     12,544
    float* weight  = scores + Mrows;                        //     12,544
    float* sums    = weight + Mrows;                        //  2,621,440
    float* a2c_out = sums + (size_t)Bn * 5 * Hn;            //  1,048,576

    hipMemsetAsync(scores, 0, Mrows * sizeof(float), stream);

    k_convert<<<(Mrows * Hn / 8) / 256, 256, 0, stream>>>(V, Vb, Mrows * Hn / 8);
    k_convert<<<(Hn * Hn / 8) / 256, 256, 0, stream>>>(att_W, attWb, Hn * Hn / 8);
    k_convert<<<(Hn * Hn / 8) / 256, 256, 0, stream>>>(ctx_W, ctxWb, Hn * Hn / 8);
    k_gather<<<Bn, 256, 0, stream>>>(emb, state, captions, timep, xtb, hb);

    // att_feats = relu(V @ att_W^T + att_b) -> bf16
    k_gemm<0, false, false><<<dim3(Hn / 128, Mrows / 128), 256, 0, stream>>>(
        Vb, attWb, nullptr, nullptr, att_b, nullptr, attfb, nullptr, nullptr,
        Mrows, Hn, Hn);
    // att_h = h_prev @ h2att_W^T + h2att_b  (f32 out)
    k_gemm<1, true, false><<<dim3(Hn / 128, Bn / 128), 256, 0, stream>>>(
        hb, h2att_W, nullptr, nullptr, h2att_b, nullptr, atth, nullptr, nullptr,
        Bn, Hn, Hn);
    // scores[m] = sum_n tanh(att_feats@ctx_W^T + ctx_b + att_h) * alpha_W
    k_gemm<3, false, false><<<dim3(Hn / 128, Mrows / 128), 256, 0, stream>>>(
        attfb, ctxWb, nullptr, nullptr, ctx_b, nullptr, scores, atth, alpha_W,
        Mrows, Hn, Hn);
    k_softmax<<<Bn, 64, 0, stream>>>(scores, weight);
    k_attres<<<dim3(Hn / 256, Bn), 256, 0, stream>>>(weight, attfb, attresb);
    // sums = xt@i2h^T + i2h_b + h@h2h^T + h2h_b   (dual, f32 out)
    k_gemm<1, true, true><<<dim3(5 * Hn / 128, Bn / 128), 256, 0, stream>>>(
        xtb, i2h_W, hb, h2h_W, i2h_b, h2h_b, sums, nullptr, nullptr,
        Bn, 5 * Hn, Hn);
    // a2c_out = att_res @ a2c_W^T + a2c_b  (f32 out)
    k_gemm<1, true, false><<<dim3(2 * Hn / 128, Bn / 128), 256, 0, stream>>>(
        attresb, a2c_W, nullptr, nullptr, a2c_b, nullptr, a2c_out, nullptr, nullptr,
        Bn, 2 * Hn, Hn);

    k_final<<<Bn * Hn / 256, 256, 0, stream>>>(sums, a2c_out, state, timep, (float*)d_out);
}